// Round 3
// baseline (706.276 us; speedup 1.0000x reference)
//
#include <hip/hip_runtime.h>
#include <stdint.h>

#define IN_DIM    1024
#define OUT_DIM   1024
#define ROWSTRIDE 1025        // x has INPUT_DIM + CONDITION_DIM columns
#define BATCH     32768
#define NBASIS    6
#define KTOT      (NBASIS * IN_DIM)   // 6144 : BT row stride (k = c*1024 + d)
#define KSTEPS    96                  // 6 c-blocks x 16 d-chunks of 64

typedef __bf16 bf16x8 __attribute__((ext_vector_type(8)));
typedef float  f32x4  __attribute__((ext_vector_type(4)));

__device__ inline unsigned short f2bf(float f) {
  union { float f; unsigned u; } v; v.f = f;
  unsigned u = v.u;
  return (unsigned short)((u + 0x7FFFu + ((u >> 16) & 1u)) >> 16);  // RNE
}

// ---------- prep 1: feats -> F bf16 [BATCH][1024]; basis -> bas_t [6][BATCH] ----------
__global__ __launch_bounds__(256) void prep_f(const float* __restrict__ x,
                                              unsigned short* __restrict__ F,
                                              float* __restrict__ bas_t) {
  const int tid = threadIdx.x;
  const int rl  = tid >> 7;        // row within pair
  const int j   = tid & 127;
  for (int rb = blockIdx.x * 2 + rl; rb < BATCH; rb += 4096) {
    const float* xr = x + (size_t)rb * ROWSTRIDE;
    unsigned short* fr = F + (size_t)rb * IN_DIM;
    #pragma unroll
    for (int i = 0; i < 4; ++i) {
      float v0 = xr[2 * j + 256 * i];
      float v1 = xr[2 * j + 1 + 256 * i];
      unsigned pw = (unsigned)f2bf(v0) | ((unsigned)f2bf(v1) << 16);
      *(unsigned*)(fr + 2 * j + 256 * i) = pw;     // coalesced 4B stores
    }
    if (j == 0) {
      float t  = xr[IN_DIM];
      float r1 = fmaxf(t - 0.25f, 0.0f);
      float r2 = fmaxf(t - 0.50f, 0.0f);
      float r3 = fmaxf(t - 0.75f, 0.0f);
      bas_t[rb]             = 1.0f;
      bas_t[BATCH + rb]     = t;
      bas_t[2 * BATCH + rb] = t * t;
      bas_t[3 * BATCH + rb] = r1 * r1;
      bas_t[4 * BATCH + rb] = r2 * r2;
      bas_t[5 * BATCH + rb] = r3 * r3;
    }
  }
}

// ---------- prep 2: weight [6144][1024] fp32 -> BT [1024][6144] bf16 ----------
__global__ void prep_wt(const float* __restrict__ w, unsigned short* __restrict__ bt) {
  __shared__ unsigned short t[32][33];
  int k0 = blockIdx.x * 32;
  int e0 = blockIdx.y * 32;
  int tid = threadIdx.x;
  #pragma unroll
  for (int p = tid; p < 1024; p += 256) {
    int kk = p >> 5, ee = p & 31;
    t[ee][kk] = f2bf(w[(size_t)(k0 + kk) * OUT_DIM + e0 + ee]);
  }
  __syncthreads();
  #pragma unroll
  for (int p = tid; p < 1024; p += 256) {
    int ee = p >> 5, kk = p & 31;
    bt[(size_t)(e0 + ee) * KTOT + k0 + kk] = t[ee][kk];
  }
}

// ---------- 256x256 GEMM, counted-vmcnt pipeline, basis folded into A staging ----------
// out[b][e] = sum_c ( sum_d bf16(bas[b][c]*F[b][d]) * BT[e][c*1024+d] ) + bias[e]
__device__ inline void gload_lds16(const unsigned short* g, unsigned short* l) {
  __builtin_amdgcn_global_load_lds((const __attribute__((address_space(1))) void*)g,
                                   (__attribute__((address_space(3))) void*)l, 16, 0, 0);
}

__device__ __attribute__((always_inline)) inline
void scale_store(uint4 w, float s, unsigned short* dst) {
  bf16x8 r;
  unsigned q0 = w.x, q1 = w.y, q2 = w.z, q3 = w.w;
  r[0] = (__bf16)(__uint_as_float(q0 << 16) * s);
  r[1] = (__bf16)(__uint_as_float(q0 & 0xFFFF0000u) * s);
  r[2] = (__bf16)(__uint_as_float(q1 << 16) * s);
  r[3] = (__bf16)(__uint_as_float(q1 & 0xFFFF0000u) * s);
  r[4] = (__bf16)(__uint_as_float(q2 << 16) * s);
  r[5] = (__bf16)(__uint_as_float(q2 & 0xFFFF0000u) * s);
  r[6] = (__bf16)(__uint_as_float(q3 << 16) * s);
  r[7] = (__bf16)(__uint_as_float(q3 & 0xFFFF0000u) * s);
  *(bf16x8*)dst = r;    // ds_write_b128 to swizzled slot
}

template<int I0>
__device__ __attribute__((always_inline)) inline
void cluster(f32x4 (&acc)[8][4], const bf16x8* afr, const bf16x8* bfr) {
  __builtin_amdgcn_s_setprio(1);
  #pragma unroll
  for (int i = 0; i < 4; ++i) {
    #pragma unroll
    for (int j = 0; j < 4; ++j)
      acc[I0 + i][j] =
          __builtin_amdgcn_mfma_f32_16x16x32_bf16(afr[i], bfr[j], acc[I0 + i][j], 0, 0, 0);
  }
  __builtin_amdgcn_s_setprio(0);
}

__global__ __launch_bounds__(512, 2) void vcl_gemm(
    const unsigned short* __restrict__ F,    // [BATCH][1024] bf16
    const unsigned short* __restrict__ BT,   // [OUT_DIM][KTOT] bf16 W^T
    const float* __restrict__ bas_t,         // [6][BATCH] fp32
    const float* __restrict__ bias,
    float* __restrict__ out) {
  // 128 KB LDS: double-buffered 256x64 A and B tiles (bf16)
  __shared__ __align__(16) unsigned short smem[65536];
  unsigned short* const sA0 = smem;
  unsigned short* const sA1 = smem + 16384;
  unsigned short* const sB0 = smem + 32768;
  unsigned short* const sB1 = smem + 49152;

  const int tid  = threadIdx.x;
  const int wv   = tid >> 6;        // 0..7
  const int lane = tid & 63;
  const int ln15 = lane & 15;
  const int quad = lane >> 4;
  const int lr   = lane >> 3;       // row within 8-row staging chunk
  const int kg   = lane & 7;        // natural k-group for A reg-staging
  const int wm   = wv >> 2;         // 0..1 : 128-row half
  const int wn   = wv & 3;          // 0..3 : 64-col quarter

  const int bm0 = (blockIdx.x >> 2) * 256;
  const int bn0 = (blockIdx.x & 3) * 256;   // fixed bn per XCD -> B strip (3MB) L2-resident

  // staging geometry (rows shared by A and B paths)
  int arow[4]; unsigned agoff[4]; int awoff[4];
  const unsigned short* gB[4]; int lboff[4];
  #pragma unroll
  for (int w = 0; w < 4; ++w) {
    arow[w]  = wv * 32 + w * 8 + lr;
    agoff[w] = (unsigned)(bm0 + arow[w]) * 1024u + (unsigned)(kg * 8);
    awoff[w] = arow[w] * 128 + ((kg ^ lr) << 4);                       // swizzled A write (bytes)
    gB[w]    = BT + (size_t)(bn0 + arow[w]) * KTOT + (kg ^ lr) * 8;    // pre-swizzled B source
    lboff[w] = (wv * 4 + w) * 512;                                     // linear B dest (elems)
  }

  // fragment read offsets (elements); slot XOR matches both staging paths
  const int slot0 = quad ^ (ln15 & 7);
  const int aoff0 = (wm * 128 + ln15) * 64 + slot0 * 8;   // ks=1 -> ^32
  const int boff0 = (wn * 64 + ln15) * 64 + slot0 * 8;

  float bias_j[4];
  #pragma unroll
  for (int jj = 0; jj < 4; ++jj) bias_j[jj] = bias[bn0 + wn * 64 + jj * 16 + ln15];

  float s_[4];
  #pragma unroll
  for (int w = 0; w < 4; ++w) s_[w] = bas_t[bm0 + arow[w]];   // c = 0

  f32x4 acc[8][4] = {};

  // ---- prologue: stage k-step 0 (A regs order BEFORE B: vmcnt accounting) ----
  {
    uint4 ad0[4];
    #pragma unroll
    for (int w = 0; w < 4; ++w) ad0[w] = *(const uint4*)(F + agoff[w]);
    #pragma unroll
    for (int w = 0; w < 4; ++w) gload_lds16(gB[w], sB0 + lboff[w]);
    #pragma unroll
    for (int w = 0; w < 4; ++w)
      scale_store(ad0[w], s_[w], (unsigned short*)((char*)sA0 + awoff[w]));
    asm volatile("s_waitcnt lgkmcnt(0)" ::: "memory");
    // B(0) left in flight; step-0 entry wait + barrier covers it
  }

  for (int t = 0; t < KSTEPS; ++t) {
    const unsigned short* sAc = (t & 1) ? sA1 : sA0;
    const unsigned short* sBc = (t & 1) ? sB1 : sB0;
    unsigned short* sAn = (t & 1) ? sA0 : sA1;
    unsigned short* sBn = (t & 1) ? sB0 : sB1;
    const int tn = (t + 1 == KSTEPS) ? 0 : (t + 1);   // wrap: last stage harmless
    const int doffA = (tn & 15) * 64;                 // d-chunk within c-block (elems)
    const unsigned offB = (unsigned)(tn * 64);        // monotone k (elems)

    // ---- entry: issue next-step loads (bas first, then A regs, then B) ----
    if ((tn & 15) == 0) {                             // c boundary: reload row scales
      const int c = tn >> 4;
      #pragma unroll
      for (int w = 0; w < 4; ++w)
        s_[w] = bas_t[(size_t)c * BATCH + bm0 + arow[w]];
    }
    uint4 ad[4];
    #pragma unroll
    for (int w = 0; w < 4; ++w) ad[w] = *(const uint4*)(F + agoff[w] + doffA);
    #pragma unroll
    for (int w = 0; w < 4; ++w) gload_lds16(gB[w] + offB, sBn + lboff[w]);

    // counted wait: drains ONLY previous step's B loads; 8 newest stay in flight
    asm volatile("s_waitcnt vmcnt(8)" ::: "memory");
    __builtin_amdgcn_s_barrier();
    __builtin_amdgcn_sched_barrier(0);

    bf16x8 afr[4], bfr[4];

    // ---- phase 0: ks=0, rows 0..63 ----
    #pragma unroll
    for (int j = 0; j < 4; ++j) bfr[j] = *(const bf16x8*)(sBc + boff0 + j * 1024);
    #pragma unroll
    for (int i = 0; i < 4; ++i) afr[i] = *(const bf16x8*)(sAc + aoff0 + i * 1024);
    cluster<0>(acc, afr, bfr);

    // ---- phase 1: ks=0, rows 64..127 ----
    #pragma unroll
    for (int i = 0; i < 4; ++i) afr[i] = *(const bf16x8*)(sAc + aoff0 + (i + 4) * 1024);
    cluster<4>(acc, afr, bfr);

    // ---- A staging for t+1 (compiler inserts vmcnt(4) for ad use) ----
    scale_store(ad[0], s_[0], (unsigned short*)((char*)sAn + awoff[0]));
    scale_store(ad[1], s_[1], (unsigned short*)((char*)sAn + awoff[1]));
    scale_store(ad[2], s_[2], (unsigned short*)((char*)sAn + awoff[2]));
    scale_store(ad[3], s_[3], (unsigned short*)((char*)sAn + awoff[3]));

    // ---- phase 2: ks=1, rows 0..63 ----
    #pragma unroll
    for (int j = 0; j < 4; ++j) bfr[j] = *(const bf16x8*)(sBc + (boff0 ^ 32) + j * 1024);
    #pragma unroll
    for (int i = 0; i < 4; ++i) afr[i] = *(const bf16x8*)(sAc + (aoff0 ^ 32) + i * 1024);
    cluster<0>(acc, afr, bfr);

    // ---- phase 3: ks=1, rows 64..127 ----
    #pragma unroll
    for (int i = 0; i < 4; ++i) afr[i] = *(const bf16x8*)(sAc + (aoff0 ^ 32) + (i + 4) * 1024);
    cluster<4>(acc, afr, bfr);

    // ---- exit: flush my ds_writes (NO vmem drain), barrier ----
    asm volatile("s_waitcnt lgkmcnt(0)" ::: "memory");
    __builtin_amdgcn_sched_barrier(0);
    __builtin_amdgcn_s_barrier();
    __builtin_amdgcn_sched_barrier(0);
  }

  // ---- epilogue: 4 groups of 64 rows via LDS for 1KB-contiguous row stores ----
  float* buf = (float*)smem;          // [64][260] fp32 = 66.6 KB
  const int ROWP = 260;
  const int erow = tid >> 3;          // 0..63
  const int echk = tid & 7;           // 8 chunks of 32 cols

  #pragma unroll
  for (int g = 0; g < 4; ++g) {
    __syncthreads();
    if (wm == (g >> 1)) {
      const int i0 = (g & 1) * 4;
      #pragma unroll
      for (int ii = 0; ii < 4; ++ii) {
        #pragma unroll
        for (int j = 0; j < 4; ++j) {
          #pragma unroll
          for (int r = 0; r < 4; ++r)
            buf[(ii * 16 + quad * 4 + r) * ROWP + wn * 64 + j * 16 + ln15] =
                acc[i0 + ii][j][r] + bias_j[j];
        }
      }
    }
    __syncthreads();
    float* orow = out + (size_t)(bm0 + g * 64 + erow) * OUT_DIM + bn0 + echk * 32;
    const float* brow = buf + erow * ROWP + echk * 32;
    #pragma unroll
    for (int e = 0; e < 8; ++e)
      *(f32x4*)(orow + e * 4) = *(const f32x4*)(brow + e * 4);
  }
}

extern "C" void kernel_launch(void* const* d_in, const int* in_sizes, int n_in,
                              void* d_out, int out_size, void* d_ws, size_t ws_size,
                              hipStream_t stream) {
  const float* x    = (const float*)d_in[0];
  const float* w    = (const float*)d_in[1];
  const float* bias = (const float*)d_in[2];
  float* out = (float*)d_out;

  // ws layout: F bf16 [32768][1024] = 64 MiB, BT bf16 [1024][6144] = 12 MiB, bas_t [6][32768] fp32
  unsigned short* F  = (unsigned short*)d_ws;
  unsigned short* BT = (unsigned short*)((char*)d_ws + (size_t)BATCH * IN_DIM * 2);
  float* bas_t = (float*)((char*)d_ws + (size_t)BATCH * IN_DIM * 2 + (size_t)OUT_DIM * KTOT * 2);

  prep_f<<<2048, 256, 0, stream>>>(x, F, bas_t);
  dim3 g2(KTOT / 32, OUT_DIM / 32);
  prep_wt<<<g2, 256, 0, stream>>>(w, BT);
  vcl_gemm<<<(BATCH / 256) * (OUT_DIM / 256), 512, 0, stream>>>(F, BT, bas_t, bias, out);
}

// Round 4
// 691.735 us; speedup vs baseline: 1.0210x; 1.0210x over previous
//
#include <hip/hip_runtime.h>
#include <stdint.h>

#define IN_DIM    1024
#define OUT_DIM   1024
#define ROWSTRIDE 1025        // x has INPUT_DIM + CONDITION_DIM columns
#define BATCH     32768
#define NBASIS    6
#define KTOT      (NBASIS * IN_DIM)   // 6144 : BT row stride (k = c*1024 + d)

typedef __bf16 bf16x8 __attribute__((ext_vector_type(8)));
typedef float  f32x4  __attribute__((ext_vector_type(4)));

__device__ inline unsigned short f2bf(float f) {
  union { float f; unsigned u; } v; v.f = f;
  unsigned u = v.u;
  return (unsigned short)((u + 0x7FFFu + ((u >> 16) & 1u)) >> 16);  // RNE
}

// ---------- prep 1: feats -> F bf16 [BATCH][1024]; basis -> bas_t [6][BATCH] ----------
__global__ __launch_bounds__(256) void prep_f(const float* __restrict__ x,
                                              unsigned short* __restrict__ F,
                                              float* __restrict__ bas_t) {
  const int tid = threadIdx.x;
  const int rl  = tid >> 7;        // row within pair
  const int j   = tid & 127;
  for (int rb = blockIdx.x * 2 + rl; rb < BATCH; rb += 4096) {
    const float* xr = x + (size_t)rb * ROWSTRIDE;
    unsigned short* fr = F + (size_t)rb * IN_DIM;
    #pragma unroll
    for (int i = 0; i < 4; ++i) {
      float v0 = xr[2 * j + 256 * i];
      float v1 = xr[2 * j + 1 + 256 * i];
      unsigned pw = (unsigned)f2bf(v0) | ((unsigned)f2bf(v1) << 16);
      *(unsigned*)(fr + 2 * j + 256 * i) = pw;     // coalesced 4B stores
    }
    if (j == 0) {
      float t  = xr[IN_DIM];
      float r1 = fmaxf(t - 0.25f, 0.0f);
      float r2 = fmaxf(t - 0.50f, 0.0f);
      float r3 = fmaxf(t - 0.75f, 0.0f);
      bas_t[rb]             = 1.0f;
      bas_t[BATCH + rb]     = t;
      bas_t[2 * BATCH + rb] = t * t;
      bas_t[3 * BATCH + rb] = r1 * r1;
      bas_t[4 * BATCH + rb] = r2 * r2;
      bas_t[5 * BATCH + rb] = r3 * r3;
    }
  }
}

// ---------- prep 2: weight [6144][1024] fp32 -> BT [1024][6144] bf16 ----------
__global__ void prep_wt(const float* __restrict__ w, unsigned short* __restrict__ bt) {
  __shared__ unsigned short t[32][33];
  int k0 = blockIdx.x * 32;
  int e0 = blockIdx.y * 32;
  int tid = threadIdx.x;
  #pragma unroll
  for (int p = tid; p < 1024; p += 256) {
    int kk = p >> 5, ee = p & 31;
    t[ee][kk] = f2bf(w[(size_t)(k0 + kk) * OUT_DIM + e0 + ee]);
  }
  __syncthreads();
  #pragma unroll
  for (int p = tid; p < 1024; p += 256) {
    int ee = p >> 5, kk = p & 31;
    bt[(size_t)(e0 + ee) * KTOT + k0 + kk] = t[ee][kk];
  }
}

// ---------- 256x256 GEMM, d-outer / c-inner, fully-covered latencies ----------
// out[b][e] = sum_d sum_c bf16(bas[b][c]*F[b][d]) * BT[e][c*1024+d] + bias[e]
__device__ inline void gload_lds16(const unsigned short* g, unsigned short* l) {
  __builtin_amdgcn_global_load_lds((const __attribute__((address_space(1))) void*)g,
                                   (__attribute__((address_space(3))) void*)l, 16, 0, 0);
}

__device__ __attribute__((always_inline)) inline
void scale_store(uint4 w, float s, unsigned short* dst) {
  bf16x8 r;
  unsigned q0 = w.x, q1 = w.y, q2 = w.z, q3 = w.w;
  r[0] = (__bf16)(__uint_as_float(q0 << 16) * s);
  r[1] = (__bf16)(__uint_as_float(q0 & 0xFFFF0000u) * s);
  r[2] = (__bf16)(__uint_as_float(q1 << 16) * s);
  r[3] = (__bf16)(__uint_as_float(q1 & 0xFFFF0000u) * s);
  r[4] = (__bf16)(__uint_as_float(q2 << 16) * s);
  r[5] = (__bf16)(__uint_as_float(q2 & 0xFFFF0000u) * s);
  r[6] = (__bf16)(__uint_as_float(q3 << 16) * s);
  r[7] = (__bf16)(__uint_as_float(q3 & 0xFFFF0000u) * s);
  *(bf16x8*)dst = r;    // ds_write_b128 to swizzled slot
}

template<int I0>
__device__ __attribute__((always_inline)) inline
void cluster(f32x4 (&acc)[8][4], const bf16x8* afr, const bf16x8* bfr) {
  __builtin_amdgcn_s_setprio(1);
  #pragma unroll
  for (int i = 0; i < 4; ++i) {
    #pragma unroll
    for (int j = 0; j < 4; ++j)
      acc[I0 + i][j] =
          __builtin_amdgcn_mfma_f32_16x16x32_bf16(afr[i], bfr[j], acc[I0 + i][j], 0, 0, 0);
  }
  __builtin_amdgcn_s_setprio(0);
}

// One (d,c) K-step. CC = c (compile-time const in unrolled body). WSTR = counted entry wait.
// Queue discipline (steady state, 4 ops per batch, oldest->newest):
//   c=0: [B(c0),B(c1),adn] -> vmcnt(8)   c=1: [B(c1),adn,B(c2)] -> vmcnt(8)
//   c=2: [adn,B(c2),B(c3)] -> vmcnt(4)   c=3..5: [B(c),B(c+1)]  -> vmcnt(4)
#define KSTEP(CC, WSTR)                                                                    \
  {                                                                                        \
    const unsigned short* sAc = ((CC) & 1) ? sA1 : sA0;                                    \
    const unsigned short* sBc = ((CC) & 1) ? sB1 : sB0;                                    \
    unsigned short* sAn = ((CC) & 1) ? sA0 : sA1;                                          \
    unsigned short* sBn = ((CC) & 1) ? sB0 : sB1;                                          \
    const unsigned offB = ((CC) < 5) ? (unsigned)((((CC) + 1) << 10) | (d << 6))           \
                                     : (unsigned)(dn1 << 6);                               \
    gload_lds16(BT + gBoff[0] + offB, sBn + lboff[0]);                                     \
    gload_lds16(BT + gBoff[1] + offB, sBn + lboff[1]);                                     \
    gload_lds16(BT + gBoff[2] + offB, sBn + lboff[2]);                                     \
    gload_lds16(BT + gBoff[3] + offB, sBn + lboff[3]);                                     \
    if ((CC) == 0) {                                                                       \
      adn[0] = *(const uint4*)(F + agoff[0] + (dn1 << 6));                                 \
      adn[1] = *(const uint4*)(F + agoff[1] + (dn1 << 6));                                 \
      adn[2] = *(const uint4*)(F + agoff[2] + (dn1 << 6));                                 \
      adn[3] = *(const uint4*)(F + agoff[3] + (dn1 << 6));                                 \
    }                                                                                      \
    asm volatile("s_waitcnt " WSTR ::: "memory");                                          \
    __builtin_amdgcn_s_barrier();                                                          \
    __builtin_amdgcn_sched_barrier(0);                                                     \
    const int ci_ = ((CC) < 5) ? (CC) + 1 : 0;                                             \
    float sc0 = bas_lds[ci_ * 256 + arow[0]];                                              \
    float sc1 = bas_lds[ci_ * 256 + arow[1]];                                              \
    float sc2 = bas_lds[ci_ * 256 + arow[2]];                                              \
    float sc3 = bas_lds[ci_ * 256 + arow[3]];                                              \
    const uint4* asrc = ((CC) < 5) ? ad : adn;                                             \
    bf16x8 afr[4], bfr[4];                                                                 \
    _Pragma("unroll")                                                                      \
    for (int j = 0; j < 4; ++j) bfr[j] = *(const bf16x8*)(sBc + boff0 + j * 1024);         \
    _Pragma("unroll")                                                                      \
    for (int i = 0; i < 4; ++i) afr[i] = *(const bf16x8*)(sAc + aoff0 + i * 1024);         \
    cluster<0>(acc, afr, bfr);                                                             \
    scale_store(asrc[0], sc0, (unsigned short*)((char*)sAn + awoff[0]));                   \
    _Pragma("unroll")                                                                      \
    for (int i = 0; i < 4; ++i) afr[i] = *(const bf16x8*)(sAc + aoff0 + (i + 4) * 1024);   \
    cluster<4>(acc, afr, bfr);                                                             \
    scale_store(asrc[1], sc1, (unsigned short*)((char*)sAn + awoff[1]));                   \
    _Pragma("unroll")                                                                      \
    for (int j = 0; j < 4; ++j) bfr[j] = *(const bf16x8*)(sBc + (boff0 ^ 32) + j * 1024);  \
    _Pragma("unroll")                                                                      \
    for (int i = 0; i < 4; ++i) afr[i] = *(const bf16x8*)(sAc + (aoff0 ^ 32) + i * 1024);  \
    cluster<0>(acc, afr, bfr);                                                             \
    scale_store(asrc[2], sc2, (unsigned short*)((char*)sAn + awoff[2]));                   \
    _Pragma("unroll")                                                                      \
    for (int i = 0; i < 4; ++i)                                                            \
      afr[i] = *(const bf16x8*)(sAc + (aoff0 ^ 32) + (i + 4) * 1024);                      \
    cluster<4>(acc, afr, bfr);                                                             \
    scale_store(asrc[3], sc3, (unsigned short*)((char*)sAn + awoff[3]));                   \
    asm volatile("s_waitcnt lgkmcnt(0)" ::: "memory");                                     \
    __builtin_amdgcn_sched_barrier(0);                                                     \
    __builtin_amdgcn_s_barrier();                                                          \
    __builtin_amdgcn_sched_barrier(0);                                                     \
  }

__global__ __launch_bounds__(512, 2) void vcl_gemm(
    const unsigned short* __restrict__ F,    // [BATCH][1024] bf16
    const unsigned short* __restrict__ BT,   // [OUT_DIM][KTOT] bf16 W^T
    const float* __restrict__ bas_t,         // [6][BATCH] fp32
    const float* __restrict__ bias,
    float* __restrict__ out) {
  // 128 KB LDS: double-buffered 256x64 A and B tiles (bf16) + 6 KB basis table
  __shared__ __align__(16) unsigned short smem[65536];
  __shared__ __align__(16) float bas_lds[NBASIS * 256];
  unsigned short* const sA0 = smem;
  unsigned short* const sA1 = smem + 16384;
  unsigned short* const sB0 = smem + 32768;
  unsigned short* const sB1 = smem + 49152;

  const int tid  = threadIdx.x;
  const int wv   = tid >> 6;        // 0..7
  const int lane = tid & 63;
  const int ln15 = lane & 15;
  const int quad = lane >> 4;
  const int lr   = lane >> 3;       // row within 8-row staging chunk
  const int kg   = lane & 7;        // natural k-group for A reg-staging
  const int wm   = wv >> 2;         // 0..1 : 128-row half
  const int wn   = wv & 3;          // 0..3 : 64-col quarter

  const int bm0 = (blockIdx.x >> 2) * 256;
  const int bn0 = (blockIdx.x & 3) * 256;   // fixed bn per XCD -> B strip (3MB) L2-resident

  // staging geometry (rows shared by A and B paths); 32-bit offsets -> saddr form
  int arow[4]; unsigned agoff[4]; int awoff[4];
  unsigned gBoff[4]; int lboff[4];
  #pragma unroll
  for (int w = 0; w < 4; ++w) {
    arow[w]  = wv * 32 + w * 8 + lr;
    agoff[w] = (unsigned)(bm0 + arow[w]) * 1024u + (unsigned)(kg * 8);
    awoff[w] = arow[w] * 128 + ((kg ^ lr) << 4);                        // swizzled A write (bytes)
    gBoff[w] = (unsigned)(bn0 + arow[w]) * (unsigned)KTOT + (unsigned)((kg ^ lr) * 8);
    lboff[w] = (wv * 4 + w) * 512;                                      // linear B dest (elems)
  }

  // fragment read offsets (elements); slot XOR matches both staging paths
  const int slot0 = quad ^ (ln15 & 7);
  const int aoff0 = (wm * 128 + ln15) * 64 + slot0 * 8;   // ks=1 -> ^32
  const int boff0 = (wn * 64 + ln15) * 64 + slot0 * 8;

  // basis table for this block's 256 rows: bas_lds[c*256 + row]
  for (int p = tid; p < NBASIS * 256; p += 512)
    bas_lds[p] = bas_t[(size_t)(p >> 8) * BATCH + bm0 + (p & 255)];
  __syncthreads();

  f32x4 acc[8][4] = {};
  uint4 ad[4], adn[4];

  // ---- prologue: stage tile (d=0,c=0) into buffer 0 ----
  #pragma unroll
  for (int w = 0; w < 4; ++w) ad[w] = *(const uint4*)(F + agoff[w]);   // F[d=0]
  #pragma unroll
  for (int w = 0; w < 4; ++w) gload_lds16(BT + gBoff[w], sB0 + lboff[w]);   // k=0
  {
    float s0 = bas_lds[arow[0]], s1 = bas_lds[arow[1]];
    float s2 = bas_lds[arow[2]], s3 = bas_lds[arow[3]];
    scale_store(ad[0], s0, (unsigned short*)((char*)sA0 + awoff[0]));
    scale_store(ad[1], s1, (unsigned short*)((char*)sA0 + awoff[1]));
    scale_store(ad[2], s2, (unsigned short*)((char*)sA0 + awoff[2]));
    scale_store(ad[3], s3, (unsigned short*)((char*)sA0 + awoff[3]));
  }
  asm volatile("s_waitcnt lgkmcnt(0)" ::: "memory");
  // B(0,0) left in flight; first KSTEP's vmcnt(8) + barrier covers it

  for (int d = 0; d < 16; ++d) {
    const int dn1 = (d + 1) & 15;   // d=15 wraps: harmless redundant loads, never consumed
    KSTEP(0, "vmcnt(8)")
    KSTEP(1, "vmcnt(8)")
    KSTEP(2, "vmcnt(4)")
    KSTEP(3, "vmcnt(4)")
    KSTEP(4, "vmcnt(4)")
    KSTEP(5, "vmcnt(4)")
    ad[0] = adn[0]; ad[1] = adn[1]; ad[2] = adn[2]; ad[3] = adn[3];   // F[d+1] becomes current
  }

  // ---- epilogue: 4 groups of 64 rows via LDS for 1KB-contiguous row stores ----
  float bias_j[4];
  #pragma unroll
  for (int jj = 0; jj < 4; ++jj) bias_j[jj] = bias[bn0 + wn * 64 + jj * 16 + ln15];

  float* buf = (float*)smem;          // [64][260] fp32 = 66.6 KB
  const int ROWP = 260;
  const int erow = tid >> 3;          // 0..63
  const int echk = tid & 7;           // 8 chunks of 32 cols

  #pragma unroll
  for (int g = 0; g < 4; ++g) {
    __syncthreads();                  // first pass also drains stray wrap-loads (full vmcnt drain)
    if (wm == (g >> 1)) {
      const int i0 = (g & 1) * 4;
      #pragma unroll
      for (int ii = 0; ii < 4; ++ii) {
        #pragma unroll
        for (int j = 0; j < 4; ++j) {
          #pragma unroll
          for (int r = 0; r < 4; ++r)
            buf[(ii * 16 + quad * 4 + r) * ROWP + wn * 64 + j * 16 + ln15] =
                acc[i0 + ii][j][r] + bias_j[j];
        }
      }
    }
    __syncthreads();
    float* orow = out + (size_t)(bm0 + g * 64 + erow) * OUT_DIM + bn0 + echk * 32;
    const float* brow = buf + erow * ROWP + echk * 32;
    #pragma unroll
    for (int e = 0; e < 8; ++e)
      *(f32x4*)(orow + e * 4) = *(const f32x4*)(brow + e * 4);
  }
}

extern "C" void kernel_launch(void* const* d_in, const int* in_sizes, int n_in,
                              void* d_out, int out_size, void* d_ws, size_t ws_size,
                              hipStream_t stream) {
  const float* x    = (const float*)d_in[0];
  const float* w    = (const float*)d_in[1];
  const float* bias = (const float*)d_in[2];
  float* out = (float*)d_out;

  // ws layout: F bf16 [32768][1024] = 64 MiB, BT bf16 [1024][6144] = 12 MiB, bas_t [6][32768] fp32
  unsigned short* F  = (unsigned short*)d_ws;
  unsigned short* BT = (unsigned short*)((char*)d_ws + (size_t)BATCH * IN_DIM * 2);
  float* bas_t = (float*)((char*)d_ws + (size_t)BATCH * IN_DIM * 2 + (size_t)OUT_DIM * KTOT * 2);

  prep_f<<<2048, 256, 0, stream>>>(x, F, bas_t);
  dim3 g2(KTOT / 32, OUT_DIM / 32);
  prep_wt<<<g2, 256, 0, stream>>>(w, BT);
  vcl_gemm<<<(BATCH / 256) * (OUT_DIM / 256), 512, 0, stream>>>(F, BT, bas_t, bias, out);
}